// Round 10
// baseline (882.099 us; speedup 1.0000x reference)
//
#include <hip/hip_runtime.h>

#define N_NODES 5000
#define N_EDGES 80000
#define MUL 128
#define MLP_IN 136
#define MLP_H 256

#define INV_F 0.08838834764831845f   /* 1/sqrt(128) */
#define C0    0.08574929257125442f   /* 1/sqrt(136) */
#define C1    0.0625f                /* 1/sqrt(256) */
#define INV_M 0.00390625f            /* 1/(sqrt(256)*16) */
#define INV_SQRT3 0.5773502691896258f

typedef float f32x4 __attribute__((ext_vector_type(4)));
typedef __bf16 bf16x8 __attribute__((ext_vector_type(8)));

#define MFMA(a, b, c) __builtin_amdgcn_mfma_f32_16x16x32_bf16((a), (b), (c), 0, 0, 0)

// transposed bf16 weight layout (element offsets, lives in d_out msg region)
#define W0_ELEMS (256 * 160)      /* K padded 136 -> 160 */
#define W1_ELEMS (256 * 256)
#define W3_ELEMS (512 * 256)
#define O0H 0
#define O0L (O0H + W0_ELEMS)
#define O1H (O0L + W0_ELEMS)
#define O1L (O1H + W1_ELEMS)
#define O2H (O1L + W1_ELEMS)
#define O2L (O2H + W1_ELEMS)
#define O3H (O2L + W1_ELEMS)
#define O3L (O3H + W3_ELEMS)
// byte offsets inside d_out msg region (10,240,000 B), all dead before k_node_post
#define WT_BYTES   1212416
#define CUR_OFF    1212416                 /* int cursor[5000] (doubles as hist) */
#define RP_OFF     (CUR_OFF + 20000)       /* int row_ptr[5001] */
#define PERM_OFF   (RP_OFF + 20004)        /* int perm[80032] (padded) */
#define TPM_OFF    1572864                 /* fallback tp_w chunk, 4224 edges */
#define TPM_EC     4224

__device__ __forceinline__ float silu_f(float x) {
    return x / (1.0f + __expf(-x));
}

__device__ __forceinline__ void split_bf16(float x, __bf16& hi, __bf16& lo) {
    hi = (__bf16)x;
    lo = (__bf16)(x - (float)hi);
}

// ---------------------------------------------------------------------------
// Weight prep: fp32 [K][N] -> transposed bf16 hi/lo [N][Kpad].
// ---------------------------------------------------------------------------
__global__ __launch_bounds__(256) void k_prep_w(
    const float* __restrict__ w0, const float* __restrict__ w1,
    const float* __restrict__ w2, const float* __restrict__ w3,
    __bf16* __restrict__ wt)
{
    int idx = blockIdx.x * 256 + threadIdx.x;
    float src; int oh, ol;
    if (idx < 40960) {                       // w0t: [256][160]
        int n = idx / 160, k = idx % 160;
        src = (k < 136) ? w0[k * 256 + n] : 0.0f;
        oh = O0H + idx; ol = O0L + idx;
    } else if (idx < 106496) {               // w1t: [256][256]
        int i = idx - 40960; int n = i >> 8, k = i & 255;
        src = w1[k * 256 + n]; oh = O1H + i; ol = O1L + i;
    } else if (idx < 172032) {               // w2t: [256][256]
        int i = idx - 106496; int n = i >> 8, k = i & 255;
        src = w2[k * 256 + n]; oh = O2H + i; ol = O2L + i;
    } else {                                 // w3t: [512][256]
        int i = idx - 172032; int n = i >> 8, k = i & 255;
        src = w3[k * 512 + n]; oh = O3H + i; ol = O3L + i;
    }
    __bf16 hi, lo; split_bf16(src, hi, lo);
    wt[oh] = hi; wt[ol] = lo;
}

// ---------------------------------------------------------------------------
// CSR build: histogram -> scan -> scatter. ~160K trivial atomics total.
// ---------------------------------------------------------------------------
__global__ __launch_bounds__(256) void k_hist(
    const int* __restrict__ edge_index, int* __restrict__ cursor,
    int* __restrict__ perm)
{
    int e = blockIdx.x * 256 + threadIdx.x;
    if (blockIdx.x == 0 && threadIdx.x < 32) perm[N_EDGES + threadIdx.x] = 0;
    if (e < N_EDGES) atomicAdd(&cursor[edge_index[N_EDGES + e]], 1);
}

__global__ __launch_bounds__(1024) void k_scan(
    int* __restrict__ cursor, int* __restrict__ row_ptr)
{
    __shared__ int A[5120], B[5120];
    int t = threadIdx.x;
    for (int i = t; i < 5120; i += 1024) A[i] = (i < N_NODES) ? cursor[i] : 0;
    __syncthreads();
    int* src = A; int* dst = B;
    for (int off = 1; off < 5120; off <<= 1) {
        for (int i = t; i < 5120; i += 1024)
            dst[i] = src[i] + ((i >= off) ? src[i - off] : 0);
        __syncthreads();
        int* tmp = src; src = dst; dst = tmp;
    }
    for (int i = t; i < N_NODES; i += 1024) {
        row_ptr[i + 1] = src[i];
        cursor[i] = (i == 0) ? 0 : src[i - 1];   // exclusive scan = scatter cursor
    }
    if (t == 0) row_ptr[0] = 0;
}

__global__ __launch_bounds__(256) void k_scatter(
    const int* __restrict__ edge_index, int* __restrict__ cursor,
    int* __restrict__ perm)
{
    int e = blockIdx.x * 256 + threadIdx.x;
    if (e < N_EDGES) {
        int pos = atomicAdd(&cursor[edge_index[N_EDGES + e]], 1);
        perm[pos] = e;
    }
}

// ---------------------------------------------------------------------------
// Kernel 1: node-level pre-GEMMs (unchanged).
// ---------------------------------------------------------------------------
__global__ __launch_bounds__(256) void k_node_pre(
    const float* __restrict__ node_feats,
    const float* __restrict__ W_up0, const float* __restrict__ W_up1,
    const float* __restrict__ W_down,
    const float* __restrict__ W_skip0, const float* __restrict__ W_skip1,
    float* __restrict__ s_up, float* __restrict__ v_up,
    float* __restrict__ down, float* __restrict__ out_sc)
{
    __shared__ float s_lds[8][MUL];
    __shared__ float v_lds[8][3 * MUL];
    const int n0 = blockIdx.x * 8;
    const int t = threadIdx.x;

    for (int idx = t; idx < 8 * 128; idx += 256) {
        int nn = idx >> 7, c4 = idx & 127;
        float4 val = ((const float4*)node_feats)[(size_t)(n0 + nn) * 128 + c4];
        int c = c4 * 4;
        if (c < 128) {
            s_lds[nn][c] = val.x; s_lds[nn][c + 1] = val.y;
            s_lds[nn][c + 2] = val.z; s_lds[nn][c + 3] = val.w;
        } else {
            int cv = c - 128;
            v_lds[nn][cv] = val.x; v_lds[nn][cv + 1] = val.y;
            v_lds[nn][cv + 2] = val.z; v_lds[nn][cv + 3] = val.w;
        }
    }
    __syncthreads();

    for (int o = t; o < 320; o += 256) {
        const float* W; int m, ld;
        if (o < 128)      { W = W_skip0; m = o;       ld = 128; }
        else if (o < 256) { W = W_up0;   m = o - 128; ld = 128; }
        else              { W = W_down;  m = o - 256; ld = 64;  }
        float acc[8] = {0,0,0,0,0,0,0,0};
        for (int k = 0; k < 128; ++k) {
            float w = W[k * ld + m];
            #pragma unroll
            for (int nn = 0; nn < 8; ++nn) acc[nn] += s_lds[nn][k] * w;
        }
        #pragma unroll
        for (int nn = 0; nn < 8; ++nn) {
            float r = acc[nn] * INV_F;
            int n = n0 + nn;
            if (o < 128)      out_sc[(size_t)n * 512 + m] = r;
            else if (o < 256) s_up[(size_t)n * 128 + m] = r;
            else              down[(size_t)n * 64 + m] = r;
        }
    }

    for (int o = t; o < 768; o += 256) {
        const float* W; int m, i; bool is_sc;
        if (o < 384) { W = W_skip1; i = o >> 7; m = o & 127; is_sc = true; }
        else { int ov = o - 384; W = W_up1; i = ov >> 7; m = ov & 127; is_sc = false; }
        float acc[8] = {0,0,0,0,0,0,0,0};
        for (int k = 0; k < 128; ++k) {
            float w = W[k * 128 + m];
            #pragma unroll
            for (int nn = 0; nn < 8; ++nn) acc[nn] += v_lds[nn][k * 3 + i] * w;
        }
        #pragma unroll
        for (int nn = 0; nn < 8; ++nn) {
            float r = acc[nn] * INV_F;
            int n = n0 + nn;
            if (is_sc) out_sc[(size_t)n * 512 + 128 + m * 3 + i] = r;
            else       v_up[(size_t)n * 384 + m * 3 + i] = r;
        }
    }
}

// ---------------------------------------------------------------------------
// Kernel 2: MFMA edge MLP over SORTED edges; writes tp_w fp32 rows.
// Layer 4 is one full 512-wide pass (64 acc VGPRs); h then dead -> LDS pool
// reused to stage 16 edge-rows ([16][516] fp32, +4 pad breaks kg bank
// aliasing) -> tp written in fully-coalesced 1KB/wave dwordx4 streams
// (round 7: scattered 64B segments -> 3x RMW amplification,
// FETCH 325MB + WRITE 509MB = the whole 484us).
// ---------------------------------------------------------------------------
__global__ __launch_bounds__(256, 4) void k_mlp(
    const float* __restrict__ edge_feats,
    const int*   __restrict__ edge_index,
    const __bf16* __restrict__ wt,
    const float* __restrict__ down,
    const int*   __restrict__ perm,
    float* __restrict__ tp, int lo, int hi)
{
    __shared__ __align__(16) unsigned char pool[36864];
    __bf16* aug_hi = (__bf16*)pool;            // [32*160], swz: col ^ ((row&3)<<3)
    __bf16* aug_lo = (__bf16*)(pool + 10240);
    __bf16* h_lo   = (__bf16*)pool;            // [32*256], swz: col ^ ((row&7)<<3)
    __bf16* h_hi   = (__bf16*)(pool + 20480);
    __shared__ int snd[32], rcv[32];

    const int t  = threadIdx.x;
    const int w  = t >> 6;
    const int l  = t & 63;
    const int ln = l & 15;
    const int kg = l >> 4;
    const int p_base = lo + blockIdx.x * 32;

    if (t < 32) {
        int e = perm[p_base + t];              // perm padded to 80032 with 0
        snd[t] = edge_index[e];
        rcv[t] = edge_index[N_EDGES + e];
        float4 ef0 = ((const float4*)edge_feats)[e * 2];
        float4 ef1 = ((const float4*)edge_feats)[e * 2 + 1];
        float ef[8] = {ef0.x, ef0.y, ef0.z, ef0.w, ef1.x, ef1.y, ef1.z, ef1.w};
        #pragma unroll
        for (int j = 0; j < 8; ++j) {
            __bf16 hi8, lo8; split_bf16(ef[j], hi8, lo8);
            int off = t * 160 + (j ^ ((t & 3) << 3));
            aug_hi[off] = hi8; aug_lo[off] = lo8;
        }
    }
    __syncthreads();

    for (int idx = t; idx < 32 * 32; idx += 256) {
        int e = idx >> 5, q = idx & 31;
        int node = (q < 16) ? snd[e] : rcv[e];
        float4 val = ((const float4*)down)[node * 16 + (q & 15)];
        int c = 8 + (q & 15) * 4 + ((q < 16) ? 0 : 64);
        float vv[4] = {val.x, val.y, val.z, val.w};
        #pragma unroll
        for (int j = 0; j < 4; ++j) {
            __bf16 hi8, lo8; split_bf16(vv[j], hi8, lo8);
            int off = e * 160 + ((c + j) ^ ((e & 3) << 3));
            aug_hi[off] = hi8; aug_lo[off] = lo8;
        }
    }
    for (int idx = t; idx < 32 * 24; idx += 256) {
        int e = idx / 24, c = 136 + idx % 24;
        int off = e * 160 + (c ^ ((e & 3) << 3));
        aug_hi[off] = (__bf16)0.0f; aug_lo[off] = (__bf16)0.0f;
    }
    __syncthreads();

    const int koff = kg * 8;

    // ---- Layer 1 ----
    {
        f32x4 acc[2][4] = {};
        for (int k0 = 0; k0 < 160; k0 += 32) {
            bf16x8 ah[2], al[2];
            #pragma unroll
            for (int rf = 0; rf < 2; ++rf) {
                int row = rf * 16 + ln;
                int off = row * 160 + ((k0 + koff) ^ ((row & 3) << 3));
                ah[rf] = *reinterpret_cast<const bf16x8*>(&aug_hi[off]);
                al[rf] = *reinterpret_cast<const bf16x8*>(&aug_lo[off]);
            }
            #pragma unroll
            for (int cf = 0; cf < 4; ++cf) {
                int col = w * 64 + cf * 16 + ln;
                size_t be = (size_t)col * 160 + k0 + koff;
                bf16x8 bh = *reinterpret_cast<const bf16x8*>(&wt[O0H + be]);
                bf16x8 bl = *reinterpret_cast<const bf16x8*>(&wt[O0L + be]);
                #pragma unroll
                for (int rf = 0; rf < 2; ++rf) {
                    acc[rf][cf] = MFMA(ah[rf], bh, acc[rf][cf]);
                    acc[rf][cf] = MFMA(ah[rf], bl, acc[rf][cf]);
                    acc[rf][cf] = MFMA(al[rf], bh, acc[rf][cf]);
                }
            }
        }
        __syncthreads();   // aug dead; h_lo overlays it
        #pragma unroll
        for (int rf = 0; rf < 2; ++rf)
            #pragma unroll
            for (int cf = 0; cf < 4; ++cf)
                #pragma unroll
                for (int reg = 0; reg < 4; ++reg) {
                    int row = rf * 16 + kg * 4 + reg;
                    int col = w * 64 + cf * 16 + ln;
                    float hv = silu_f(acc[rf][cf][reg] * C0);
                    __bf16 hi8, lo8; split_bf16(hv, hi8, lo8);
                    int off = row * 256 + (col ^ ((row & 7) << 3));
                    h_hi[off] = hi8; h_lo[off] = lo8;
                }
    }
    __syncthreads();

    // ---- Layers 2,3 ----
    #pragma unroll 1
    for (int layer = 0; layer < 2; ++layer) {
        const __bf16* WH = wt + (layer ? O2H : O1H);
        const __bf16* WL = wt + (layer ? O2L : O1L);
        f32x4 acc[2][4] = {};
        for (int k0 = 0; k0 < 256; k0 += 32) {
            bf16x8 ah[2], al[2];
            #pragma unroll
            for (int rf = 0; rf < 2; ++rf) {
                int row = rf * 16 + ln;
                int off = row * 256 + ((k0 + koff) ^ ((row & 7) << 3));
                ah[rf] = *reinterpret_cast<const bf16x8*>(&h_hi[off]);
                al[rf] = *reinterpret_cast<const bf16x8*>(&h_lo[off]);
            }
            #pragma unroll
            for (int cf = 0; cf < 4; ++cf) {
                int col = w * 64 + cf * 16 + ln;
                size_t be = (size_t)col * 256 + k0 + koff;
                bf16x8 bh = *reinterpret_cast<const bf16x8*>(&WH[be]);
                bf16x8 bl = *reinterpret_cast<const bf16x8*>(&WL[be]);
                #pragma unroll
                for (int rf = 0; rf < 2; ++rf) {
                    acc[rf][cf] = MFMA(ah[rf], bh, acc[rf][cf]);
                    acc[rf][cf] = MFMA(ah[rf], bl, acc[rf][cf]);
                    acc[rf][cf] = MFMA(al[rf], bh, acc[rf][cf]);
                }
            }
        }
        __syncthreads();
        #pragma unroll
        for (int rf = 0; rf < 2; ++rf)
            #pragma unroll
            for (int cf = 0; cf < 4; ++cf)
                #pragma unroll
                for (int reg = 0; reg < 4; ++reg) {
                    int row = rf * 16 + kg * 4 + reg;
                    int col = w * 64 + cf * 16 + ln;
                    float hv = silu_f(acc[rf][cf][reg] * C1);
                    __bf16 hi8, lo8; split_bf16(hv, hi8, lo8);
                    int off = row * 256 + (col ^ ((row & 7) << 3));
                    h_hi[off] = hi8; h_lo[off] = lo8;
                }
        __syncthreads();
    }

    // ---- Layer 4: single full 512-wide pass, acc4[rf][q*2+s] (64 VGPRs) ----
    f32x4 acc4[2][8] = {};
    for (int k0 = 0; k0 < 256; k0 += 32) {
        bf16x8 ah[2], al[2];
        #pragma unroll
        for (int rf = 0; rf < 2; ++rf) {
            int row = rf * 16 + ln;
            int off = row * 256 + ((k0 + koff) ^ ((row & 7) << 3));
            ah[rf] = *reinterpret_cast<const bf16x8*>(&h_hi[off]);
            al[rf] = *reinterpret_cast<const bf16x8*>(&h_lo[off]);
        }
        #pragma unroll
        for (int q = 0; q < 4; ++q)
            #pragma unroll
            for (int s2 = 0; s2 < 2; ++s2) {
                int col = q * 128 + w * 32 + s2 * 16 + ln;
                size_t be = (size_t)col * 256 + k0 + koff;
                bf16x8 bh = *reinterpret_cast<const bf16x8*>(&wt[O3H + be]);
                bf16x8 bl = *reinterpret_cast<const bf16x8*>(&wt[O3L + be]);
                int f = q * 2 + s2;
                #pragma unroll
                for (int rf = 0; rf < 2; ++rf) {
                    acc4[rf][f] = MFMA(ah[rf], bh, acc4[rf][f]);
                    acc4[rf][f] = MFMA(ah[rf], bl, acc4[rf][f]);
                    acc4[rf][f] = MFMA(al[rf], bh, acc4[rf][f]);
                }
            }
    }

    // ---- stage 16 rows at a time in LDS, write tp coalesced ----
    __syncthreads();                 // all h reads done; pool reusable
    float* rows = (float*)pool;      // [16][516] fp32 (pad 4 breaks kg aliasing)
    #pragma unroll 1
    for (int rf = 0; rf < 2; ++rf) {
        #pragma unroll
        for (int q = 0; q < 4; ++q)
            #pragma unroll
            for (int s2 = 0; s2 < 2; ++s2)
                #pragma unroll
                for (int reg = 0; reg < 4; ++reg) {
                    int row = kg * 4 + reg;                    // 0..15
                    int col = q * 128 + w * 32 + s2 * 16 + ln;
                    rows[row * 516 + col] = acc4[rf][q * 2 + s2][reg] * C1;
                }
        __syncthreads();
        for (int j = t; j < 2048; j += 256) {    // 16 rows x 128 float4
            int row = j >> 7, c4 = j & 127;
            int p = p_base + rf * 16 + row;
            if (p < hi) {
                float4 v = *reinterpret_cast<const float4*>(&rows[row * 516 + c4 * 4]);
                *reinterpret_cast<float4*>(tp + (size_t)(p - lo) * 512 + c4 * 4) = v;
            }
        }
        __syncthreads();
    }
}

// ---------------------------------------------------------------------------
// Gather segment-sum: one block per receiver node, thread t owns channel u=t.
// Reads contiguous tp_w rows + sender s_up/v_up; accumulates in registers;
// writes ms/mv exclusively (+= across chunk launches). ZERO atomics.
// ---------------------------------------------------------------------------
__global__ __launch_bounds__(128) void k_gather(
    const float* __restrict__ tp, const int* __restrict__ perm,
    const int* __restrict__ row_ptr, const int* __restrict__ edge_index,
    const float* __restrict__ edge_attrs,
    const float* __restrict__ s_up, const float* __restrict__ v_up,
    float* __restrict__ ms, float* __restrict__ mv, int lo, int hi)
{
    int n = blockIdx.x;
    int p0 = row_ptr[n], p1 = row_ptr[n + 1];
    if (p0 < lo) p0 = lo;
    if (p1 > hi) p1 = hi;
    if (p0 >= p1) return;
    const int u = threadIdx.x;   // 0..127
    float ms0 = 0.f, ms1 = 0.f, a0 = 0.f, a1 = 0.f, a2 = 0.f;
    float b0 = 0.f, b1 = 0.f, b2 = 0.f;
    for (int p = p0; p < p1; ++p) {
        int e = perm[p];
        int sn = edge_index[e];
        float y0  = edge_attrs[e * 4 + 0];
        float y1a = edge_attrs[e * 4 + 1];
        float y1b = edge_attrs[e * 4 + 2];
        float y1c = edge_attrs[e * 4 + 3];
        const float* tr = tp + (size_t)(p - lo) * 512;
        float wA = tr[u], wB = tr[128 + u], wC = tr[256 + u], wD = tr[384 + u];
        float xs = s_up[sn * 128 + u];
        const float* xvp = v_up + sn * 384 + u * 3;
        float xv0 = xvp[0], xv1 = xvp[1], xv2 = xvp[2];
        ms0 += wA * xs * y0;
        float dot = xv0 * y1a + xv1 * y1b + xv2 * y1c;
        ms1 += wD * dot * INV_SQRT3;
        float q = wB * xs * INV_SQRT3;
        a0 += q * y1a; a1 += q * y1b; a2 += q * y1c;
        float r = wC * y0 * INV_SQRT3;
        b0 += r * xv0; b1 += r * xv1; b2 += r * xv2;
    }
    float* msp = ms + (size_t)n * 256;
    msp[u] += ms0; msp[128 + u] += ms1;
    float* mvp = mv + (size_t)n * 768 + u * 3;
    mvp[0] += a0; mvp[1] += a1; mvp[2] += a2;
    mvp[384] += b0; mvp[385] += b1; mvp[386] += b2;
}

// ---------------------------------------------------------------------------
// Kernel 3: node-level post-GEMMs (unchanged).
// ---------------------------------------------------------------------------
__global__ __launch_bounds__(256) void k_node_post(
    const float* __restrict__ ms, const float* __restrict__ mv,
    const float* __restrict__ W_lin0, const float* __restrict__ W_lin1,
    float* __restrict__ msg)
{
    __shared__ float ms_lds[8][256];
    __shared__ float mv_lds[8][768];
    const int n0 = blockIdx.x * 8;
    const int t = threadIdx.x;

    for (int idx = t; idx < 8 * 256; idx += 256) {
        int nn = idx >> 8, c4 = idx & 255;
        if (c4 < 64) {
            float4 v = ((const float4*)ms)[(size_t)(n0 + nn) * 64 + c4];
            int c = c4 * 4;
            ms_lds[nn][c] = v.x; ms_lds[nn][c + 1] = v.y;
            ms_lds[nn][c + 2] = v.z; ms_lds[nn][c + 3] = v.w;
        } else {
            int q = c4 - 64;
            float4 v = ((const float4*)mv)[(size_t)(n0 + nn) * 192 + q];
            int c = q * 4;
            mv_lds[nn][c] = v.x; mv_lds[nn][c + 1] = v.y;
            mv_lds[nn][c + 2] = v.z; mv_lds[nn][c + 3] = v.w;
        }
    }
    __syncthreads();

    for (int o = t; o < 512; o += 256) {
        float acc[8] = {0,0,0,0,0,0,0,0};
        if (o < 128) {
            int m = o;
            for (int c = 0; c < 256; ++c) {
                float w = W_lin0[c * 128 + m];
                #pragma unroll
                for (int nn = 0; nn < 8; ++nn) acc[nn] += ms_lds[nn][c] * w;
            }
            #pragma unroll
            for (int nn = 0; nn < 8; ++nn)
                msg[(size_t)(n0 + nn) * 512 + m * 4] = acc[nn] * INV_M;
        } else {
            int ov = o - 128;
            int i = ov >> 7, m = ov & 127;
            for (int c = 0; c < 256; ++c) {
                float w = W_lin1[c * 128 + m];
                #pragma unroll
                for (int nn = 0; nn < 8; ++nn) acc[nn] += mv_lds[nn][c * 3 + i] * w;
            }
            #pragma unroll
            for (int nn = 0; nn < 8; ++nn)
                msg[(size_t)(n0 + nn) * 512 + m * 4 + 1 + i] = acc[nn] * INV_M;
        }
    }
}

// ---------------------------------------------------------------------------
extern "C" void kernel_launch(void* const* d_in, const int* in_sizes, int n_in,
                              void* d_out, int out_size, void* d_ws, size_t ws_size,
                              hipStream_t stream) {
    (void)in_sizes; (void)n_in; (void)out_size;

    const float* node_feats = (const float*)d_in[1];
    const float* edge_attrs = (const float*)d_in[2];
    const float* edge_feats = (const float*)d_in[3];
    const int*   edge_index = (const int*)d_in[4];
    const float* W_up0   = (const float*)d_in[5];
    const float* W_up1   = (const float*)d_in[6];
    const float* W_down  = (const float*)d_in[7];
    const float* mlp_w0  = (const float*)d_in[8];
    const float* mlp_w1  = (const float*)d_in[9];
    const float* mlp_w2  = (const float*)d_in[10];
    const float* mlp_w3  = (const float*)d_in[11];
    const float* W_lin0  = (const float*)d_in[12];
    const float* W_lin1  = (const float*)d_in[13];
    const float* W_skip0 = (const float*)d_in[14];
    const float* W_skip1 = (const float*)d_in[15];

    float* out = (float*)d_out;
    float* msg = out;                        // 10.24 MB, written LAST
    float* sc  = out + N_NODES * 512;

    // msg region hosts (all dead before k_node_post): wt, CSR, fallback tp_w
    char* outb = (char*)d_out;
    __bf16* wt   = (__bf16*)outb;
    int* cursor  = (int*)(outb + CUR_OFF);
    int* row_ptr = (int*)(outb + RP_OFF);
    int* perm    = (int*)(outb + PERM_OFF);

    // ws: fixed 30.72 MB + optional tp_w chunk
    float* s_up = (float*)d_ws;              // 640,000 f
    float* v_up = s_up + N_NODES * 128;      // 1,920,000 f
    float* down = v_up + N_NODES * 384;      // 320,000 f
    float* ms   = down + N_NODES * 64;       // 1,280,000 f
    float* mv   = ms + N_NODES * 256;        // 3,840,000 f -> end 8,000,000 f
    const size_t fixed_f = 8000000;

    // choose tp_w chunk placement/size from ws_size (runtime, same every call)
    long long spare = (long long)ws_size - (long long)(fixed_f * 4);
    long long ecws = (spare > 0) ? ((spare / 2048) & ~31LL) : 0;
    float* tp; int Ec;
    if (ecws >= 4608) {
        Ec = (int)(ecws > N_EDGES ? N_EDGES : ecws);
        tp = (float*)d_ws + fixed_f;
    } else {
        Ec = TPM_EC;
        tp = (float*)(outb + TPM_OFF);
    }

    hipMemsetAsync(ms, 0, (size_t)(N_NODES * 256 + N_NODES * 768) * sizeof(float), stream);
    hipMemsetAsync(cursor, 0, N_NODES * sizeof(int), stream);

    k_prep_w<<<1184, 256, 0, stream>>>(mlp_w0, mlp_w1, mlp_w2, mlp_w3, wt);
    k_hist<<<(N_EDGES + 255) / 256, 256, 0, stream>>>(edge_index, cursor, perm);
    k_node_pre<<<N_NODES / 8, 256, 0, stream>>>(
        node_feats, W_up0, W_up1, W_down, W_skip0, W_skip1,
        s_up, v_up, down, sc);
    k_scan<<<1, 1024, 0, stream>>>(cursor, row_ptr);
    k_scatter<<<(N_EDGES + 255) / 256, 256, 0, stream>>>(edge_index, cursor, perm);

    for (int lo = 0; lo < N_EDGES; lo += Ec) {
        int hi = lo + Ec; if (hi > N_EDGES) hi = N_EDGES;
        int nb = (hi - lo + 31) / 32;
        k_mlp<<<nb, 256, 0, stream>>>(edge_feats, edge_index, wt, down, perm, tp, lo, hi);
        k_gather<<<N_NODES, 128, 0, stream>>>(tp, perm, row_ptr, edge_index,
                                              edge_attrs, s_up, v_up, ms, mv, lo, hi);
    }

    k_node_post<<<N_NODES / 8, 256, 0, stream>>>(ms, mv, W_lin0, W_lin1, msg);
}

// Round 12
// 708.197 us; speedup vs baseline: 1.2456x; 1.2456x over previous
//
#include <hip/hip_runtime.h>

#define N_NODES 5000
#define N_EDGES 80000
#define MUL 128
#define MLP_IN 136
#define MLP_H 256

#define INV_F 0.08838834764831845f   /* 1/sqrt(128) */
#define C0    0.08574929257125442f   /* 1/sqrt(136) */
#define C1    0.0625f                /* 1/sqrt(256) */
#define INV_M 0.00390625f            /* 1/(sqrt(256)*16) */
#define INV_SQRT3 0.5773502691896258f

typedef float f32x4 __attribute__((ext_vector_type(4)));
typedef __bf16 bf16x8 __attribute__((ext_vector_type(8)));

#define MFMA(a, b, c) __builtin_amdgcn_mfma_f32_16x16x32_bf16((a), (b), (c), 0, 0, 0)

// transposed bf16 weight layout (element offsets, lives in d_out msg region)
#define W0_ELEMS (256 * 160)      /* K padded 136 -> 160 */
#define W1_ELEMS (256 * 256)
#define W3_ELEMS (512 * 256)
#define O0H 0
#define O0L (O0H + W0_ELEMS)
#define O1H (O0L + W0_ELEMS)
#define O1L (O1H + W1_ELEMS)
#define O2H (O1L + W1_ELEMS)
#define O2L (O2H + W1_ELEMS)
#define O3H (O2L + W1_ELEMS)
#define O3L (O3H + W3_ELEMS)
// byte offsets inside d_out msg region (10,240,000 B), all dead before k_node_post
#define WT_BYTES   1212416
#define CUR_OFF    1212416                 /* int cursor[5000] (doubles as hist) */
#define RP_OFF     (CUR_OFF + 20000)       /* int row_ptr[5001] */
#define PERM_OFF   (RP_OFF + 20004)        /* int perm[80032] (padded) */
#define TPM_OFF    1572864                 /* fallback tp_w chunk, 4224 edges */
#define TPM_EC     4224

__device__ __forceinline__ float silu_f(float x) {
    return x / (1.0f + __expf(-x));
}

__device__ __forceinline__ void split_bf16(float x, __bf16& hi, __bf16& lo) {
    hi = (__bf16)x;
    lo = (__bf16)(x - (float)hi);
}

// ---------------------------------------------------------------------------
// Weight prep: fp32 [K][N] -> transposed bf16 hi/lo [N][Kpad].
// ---------------------------------------------------------------------------
__global__ __launch_bounds__(256) void k_prep_w(
    const float* __restrict__ w0, const float* __restrict__ w1,
    const float* __restrict__ w2, const float* __restrict__ w3,
    __bf16* __restrict__ wt)
{
    int idx = blockIdx.x * 256 + threadIdx.x;
    float src; int oh, ol;
    if (idx < 40960) {                       // w0t: [256][160]
        int n = idx / 160, k = idx % 160;
        src = (k < 136) ? w0[k * 256 + n] : 0.0f;
        oh = O0H + idx; ol = O0L + idx;
    } else if (idx < 106496) {               // w1t: [256][256]
        int i = idx - 40960; int n = i >> 8, k = i & 255;
        src = w1[k * 256 + n]; oh = O1H + i; ol = O1L + i;
    } else if (idx < 172032) {               // w2t: [256][256]
        int i = idx - 106496; int n = i >> 8, k = i & 255;
        src = w2[k * 256 + n]; oh = O2H + i; ol = O2L + i;
    } else {                                 // w3t: [512][256]
        int i = idx - 172032; int n = i >> 8, k = i & 255;
        src = w3[k * 512 + n]; oh = O3H + i; ol = O3L + i;
    }
    __bf16 hi, lo; split_bf16(src, hi, lo);
    wt[oh] = hi; wt[ol] = lo;
}

// ---------------------------------------------------------------------------
// CSR build: histogram -> scan -> scatter. ~160K trivial atomics total.
// ---------------------------------------------------------------------------
__global__ __launch_bounds__(256) void k_hist(
    const int* __restrict__ edge_index, int* __restrict__ cursor,
    int* __restrict__ perm)
{
    int e = blockIdx.x * 256 + threadIdx.x;
    if (blockIdx.x == 0 && threadIdx.x < 32) perm[N_EDGES + threadIdx.x] = 0;
    if (e < N_EDGES) atomicAdd(&cursor[edge_index[N_EDGES + e]], 1);
}

__global__ __launch_bounds__(1024) void k_scan(
    int* __restrict__ cursor, int* __restrict__ row_ptr)
{
    __shared__ int A[5120], B[5120];
    int t = threadIdx.x;
    for (int i = t; i < 5120; i += 1024) A[i] = (i < N_NODES) ? cursor[i] : 0;
    __syncthreads();
    int* src = A; int* dst = B;
    for (int off = 1; off < 5120; off <<= 1) {
        for (int i = t; i < 5120; i += 1024)
            dst[i] = src[i] + ((i >= off) ? src[i - off] : 0);
        __syncthreads();
        int* tmp = src; src = dst; dst = tmp;
    }
    for (int i = t; i < N_NODES; i += 1024) {
        row_ptr[i + 1] = src[i];
        cursor[i] = (i == 0) ? 0 : src[i - 1];   // exclusive scan = scatter cursor
    }
    if (t == 0) row_ptr[0] = 0;
}

__global__ __launch_bounds__(256) void k_scatter(
    const int* __restrict__ edge_index, int* __restrict__ cursor,
    int* __restrict__ perm)
{
    int e = blockIdx.x * 256 + threadIdx.x;
    if (e < N_EDGES) {
        int pos = atomicAdd(&cursor[edge_index[N_EDGES + e]], 1);
        perm[pos] = e;
    }
}

// ---------------------------------------------------------------------------
// Kernel 1: node-level pre-GEMMs (unchanged).
// ---------------------------------------------------------------------------
__global__ __launch_bounds__(256) void k_node_pre(
    const float* __restrict__ node_feats,
    const float* __restrict__ W_up0, const float* __restrict__ W_up1,
    const float* __restrict__ W_down,
    const float* __restrict__ W_skip0, const float* __restrict__ W_skip1,
    float* __restrict__ s_up, float* __restrict__ v_up,
    float* __restrict__ down, float* __restrict__ out_sc)
{
    __shared__ float s_lds[8][MUL];
    __shared__ float v_lds[8][3 * MUL];
    const int n0 = blockIdx.x * 8;
    const int t = threadIdx.x;

    for (int idx = t; idx < 8 * 128; idx += 256) {
        int nn = idx >> 7, c4 = idx & 127;
        float4 val = ((const float4*)node_feats)[(size_t)(n0 + nn) * 128 + c4];
        int c = c4 * 4;
        if (c < 128) {
            s_lds[nn][c] = val.x; s_lds[nn][c + 1] = val.y;
            s_lds[nn][c + 2] = val.z; s_lds[nn][c + 3] = val.w;
        } else {
            int cv = c - 128;
            v_lds[nn][cv] = val.x; v_lds[nn][cv + 1] = val.y;
            v_lds[nn][cv + 2] = val.z; v_lds[nn][cv + 3] = val.w;
        }
    }
    __syncthreads();

    for (int o = t; o < 320; o += 256) {
        const float* W; int m, ld;
        if (o < 128)      { W = W_skip0; m = o;       ld = 128; }
        else if (o < 256) { W = W_up0;   m = o - 128; ld = 128; }
        else              { W = W_down;  m = o - 256; ld = 64;  }
        float acc[8] = {0,0,0,0,0,0,0,0};
        for (int k = 0; k < 128; ++k) {
            float w = W[k * ld + m];
            #pragma unroll
            for (int nn = 0; nn < 8; ++nn) acc[nn] += s_lds[nn][k] * w;
        }
        #pragma unroll
        for (int nn = 0; nn < 8; ++nn) {
            float r = acc[nn] * INV_F;
            int n = n0 + nn;
            if (o < 128)      out_sc[(size_t)n * 512 + m] = r;
            else if (o < 256) s_up[(size_t)n * 128 + m] = r;
            else              down[(size_t)n * 64 + m] = r;
        }
    }

    for (int o = t; o < 768; o += 256) {
        const float* W; int m, i; bool is_sc;
        if (o < 384) { W = W_skip1; i = o >> 7; m = o & 127; is_sc = true; }
        else { int ov = o - 384; W = W_up1; i = ov >> 7; m = ov & 127; is_sc = false; }
        float acc[8] = {0,0,0,0,0,0,0,0};
        for (int k = 0; k < 128; ++k) {
            float w = W[k * 128 + m];
            #pragma unroll
            for (int nn = 0; nn < 8; ++nn) acc[nn] += v_lds[nn][k * 3 + i] * w;
        }
        #pragma unroll
        for (int nn = 0; nn < 8; ++nn) {
            float r = acc[nn] * INV_F;
            int n = n0 + nn;
            if (is_sc) out_sc[(size_t)n * 512 + 128 + m * 3 + i] = r;
            else       v_up[(size_t)n * 384 + m * 3 + i] = r;
        }
    }
}

// ---------------------------------------------------------------------------
// Kernel 2: MFMA edge MLP over SORTED edges; writes tp_w fp32 rows.
// Round-11 fix: __launch_bounds__(256) WITHOUT the min-4-waves clamp.
// Round 10 showed the (256,4) clamp forced a 64-VGPR allocation while the
// single-pass layer 4 keeps 64 floats of accumulator live -> scratch spill
// (WRITE 509MB->1.52GB, FETCH->577MB, dur 484->607us). Round 3's identical
// layer-4 shape with no clamp compiled to 112 VGPR, no spill; 112 VGPR still
// gives 4 waves/SIMD so occupancy is unchanged (LDS 37.4KB -> 4 blocks/CU).
// ---------------------------------------------------------------------------
__global__ __launch_bounds__(256) void k_mlp(
    const float* __restrict__ edge_feats,
    const int*   __restrict__ edge_index,
    const __bf16* __restrict__ wt,
    const float* __restrict__ down,
    const int*   __restrict__ perm,
    float* __restrict__ tp, int lo, int hi)
{
    __shared__ __align__(16) unsigned char pool[36864];
    __bf16* aug_hi = (__bf16*)pool;            // [32*160], swz: col ^ ((row&3)<<3)
    __bf16* aug_lo = (__bf16*)(pool + 10240);
    __bf16* h_lo   = (__bf16*)pool;            // [32*256], swz: col ^ ((row&7)<<3)
    __bf16* h_hi   = (__bf16*)(pool + 20480);
    __shared__ int snd[32], rcv[32];

    const int t  = threadIdx.x;
    const int w  = t >> 6;
    const int l  = t & 63;
    const int ln = l & 15;
    const int kg = l >> 4;
    const int p_base = lo + blockIdx.x * 32;

    if (t < 32) {
        int e = perm[p_base + t];              // perm padded to 80032 with 0
        snd[t] = edge_index[e];
        rcv[t] = edge_index[N_EDGES + e];
        float4 ef0 = ((const float4*)edge_feats)[e * 2];
        float4 ef1 = ((const float4*)edge_feats)[e * 2 + 1];
        float ef[8] = {ef0.x, ef0.y, ef0.z, ef0.w, ef1.x, ef1.y, ef1.z, ef1.w};
        #pragma unroll
        for (int j = 0; j < 8; ++j) {
            __bf16 hi8, lo8; split_bf16(ef[j], hi8, lo8);
            int off = t * 160 + (j ^ ((t & 3) << 3));
            aug_hi[off] = hi8; aug_lo[off] = lo8;
        }
    }
    __syncthreads();

    for (int idx = t; idx < 32 * 32; idx += 256) {
        int e = idx >> 5, q = idx & 31;
        int node = (q < 16) ? snd[e] : rcv[e];
        float4 val = ((const float4*)down)[node * 16 + (q & 15)];
        int c = 8 + (q & 15) * 4 + ((q < 16) ? 0 : 64);
        float vv[4] = {val.x, val.y, val.z, val.w};
        #pragma unroll
        for (int j = 0; j < 4; ++j) {
            __bf16 hi8, lo8; split_bf16(vv[j], hi8, lo8);
            int off = e * 160 + ((c + j) ^ ((e & 3) << 3));
            aug_hi[off] = hi8; aug_lo[off] = lo8;
        }
    }
    for (int idx = t; idx < 32 * 24; idx += 256) {
        int e = idx / 24, c = 136 + idx % 24;
        int off = e * 160 + (c ^ ((e & 3) << 3));
        aug_hi[off] = (__bf16)0.0f; aug_lo[off] = (__bf16)0.0f;
    }
    __syncthreads();

    const int koff = kg * 8;

    // ---- Layer 1 ----
    {
        f32x4 acc[2][4] = {};
        for (int k0 = 0; k0 < 160; k0 += 32) {
            bf16x8 ah[2], al[2];
            #pragma unroll
            for (int rf = 0; rf < 2; ++rf) {
                int row = rf * 16 + ln;
                int off = row * 160 + ((k0 + koff) ^ ((row & 3) << 3));
                ah[rf] = *reinterpret_cast<const bf16x8*>(&aug_hi[off]);
                al[rf] = *reinterpret_cast<const bf16x8*>(&aug_lo[off]);
            }
            #pragma unroll
            for (int cf = 0; cf < 4; ++cf) {
                int col = w * 64 + cf * 16 + ln;
                size_t be = (size_t)col * 160 + k0 + koff;
                bf16x8 bh = *reinterpret_cast<const bf16x8*>(&wt[O0H + be]);
                bf16x8 bl = *reinterpret_cast<const bf16x8*>(&wt[O0L + be]);
                #pragma unroll
                for (int rf = 0; rf < 2; ++rf) {
                    acc[rf][cf] = MFMA(ah[rf], bh, acc[rf][cf]);
                    acc[rf][cf] = MFMA(ah[rf], bl, acc[rf][cf]);
                    acc[rf][cf] = MFMA(al[rf], bh, acc[rf][cf]);
                }
            }
        }
        __syncthreads();   // aug dead; h_lo overlays it
        #pragma unroll
        for (int rf = 0; rf < 2; ++rf)
            #pragma unroll
            for (int cf = 0; cf < 4; ++cf)
                #pragma unroll
                for (int reg = 0; reg < 4; ++reg) {
                    int row = rf * 16 + kg * 4 + reg;
                    int col = w * 64 + cf * 16 + ln;
                    float hv = silu_f(acc[rf][cf][reg] * C0);
                    __bf16 hi8, lo8; split_bf16(hv, hi8, lo8);
                    int off = row * 256 + (col ^ ((row & 7) << 3));
                    h_hi[off] = hi8; h_lo[off] = lo8;
                }
    }
    __syncthreads();

    // ---- Layers 2,3 ----
    #pragma unroll 1
    for (int layer = 0; layer < 2; ++layer) {
        const __bf16* WH = wt + (layer ? O2H : O1H);
        const __bf16* WL = wt + (layer ? O2L : O1L);
        f32x4 acc[2][4] = {};
        for (int k0 = 0; k0 < 256; k0 += 32) {
            bf16x8 ah[2], al[2];
            #pragma unroll
            for (int rf = 0; rf < 2; ++rf) {
                int row = rf * 16 + ln;
                int off = row * 256 + ((k0 + koff) ^ ((row & 7) << 3));
                ah[rf] = *reinterpret_cast<const bf16x8*>(&h_hi[off]);
                al[rf] = *reinterpret_cast<const bf16x8*>(&h_lo[off]);
            }
            #pragma unroll
            for (int cf = 0; cf < 4; ++cf) {
                int col = w * 64 + cf * 16 + ln;
                size_t be = (size_t)col * 256 + k0 + koff;
                bf16x8 bh = *reinterpret_cast<const bf16x8*>(&WH[be]);
                bf16x8 bl = *reinterpret_cast<const bf16x8*>(&WL[be]);
                #pragma unroll
                for (int rf = 0; rf < 2; ++rf) {
                    acc[rf][cf] = MFMA(ah[rf], bh, acc[rf][cf]);
                    acc[rf][cf] = MFMA(ah[rf], bl, acc[rf][cf]);
                    acc[rf][cf] = MFMA(al[rf], bh, acc[rf][cf]);
                }
            }
        }
        __syncthreads();
        #pragma unroll
        for (int rf = 0; rf < 2; ++rf)
            #pragma unroll
            for (int cf = 0; cf < 4; ++cf)
                #pragma unroll
                for (int reg = 0; reg < 4; ++reg) {
                    int row = rf * 16 + kg * 4 + reg;
                    int col = w * 64 + cf * 16 + ln;
                    float hv = silu_f(acc[rf][cf][reg] * C1);
                    __bf16 hi8, lo8; split_bf16(hv, hi8, lo8);
                    int off = row * 256 + (col ^ ((row & 7) << 3));
                    h_hi[off] = hi8; h_lo[off] = lo8;
                }
        __syncthreads();
    }

    // ---- Layer 4: single full 512-wide pass, acc4[rf][q*2+s] (64 VGPRs) ----
    f32x4 acc4[2][8] = {};
    for (int k0 = 0; k0 < 256; k0 += 32) {
        bf16x8 ah[2], al[2];
        #pragma unroll
        for (int rf = 0; rf < 2; ++rf) {
            int row = rf * 16 + ln;
            int off = row * 256 + ((k0 + koff) ^ ((row & 7) << 3));
            ah[rf] = *reinterpret_cast<const bf16x8*>(&h_hi[off]);
            al[rf] = *reinterpret_cast<const bf16x8*>(&h_lo[off]);
        }
        #pragma unroll
        for (int q = 0; q < 4; ++q)
            #pragma unroll
            for (int s2 = 0; s2 < 2; ++s2) {
                int col = q * 128 + w * 32 + s2 * 16 + ln;
                size_t be = (size_t)col * 256 + k0 + koff;
                bf16x8 bh = *reinterpret_cast<const bf16x8*>(&wt[O3H + be]);
                bf16x8 bl = *reinterpret_cast<const bf16x8*>(&wt[O3L + be]);
                int f = q * 2 + s2;
                #pragma unroll
                for (int rf = 0; rf < 2; ++rf) {
                    acc4[rf][f] = MFMA(ah[rf], bh, acc4[rf][f]);
                    acc4[rf][f] = MFMA(ah[rf], bl, acc4[rf][f]);
                    acc4[rf][f] = MFMA(al[rf], bh, acc4[rf][f]);
                }
            }
    }

    // ---- stage 16 rows at a time in LDS, write tp coalesced ----
    __syncthreads();                 // all h reads done; pool reusable
    float* rows = (float*)pool;      // [16][516] fp32 (pad 4 breaks kg aliasing)
    #pragma unroll 1
    for (int rf = 0; rf < 2; ++rf) {
        #pragma unroll
        for (int q = 0; q < 4; ++q)
            #pragma unroll
            for (int s2 = 0; s2 < 2; ++s2)
                #pragma unroll
                for (int reg = 0; reg < 4; ++reg) {
                    int row = kg * 4 + reg;                    // 0..15
                    int col = q * 128 + w * 32 + s2 * 16 + ln;
                    rows[row * 516 + col] = acc4[rf][q * 2 + s2][reg] * C1;
                }
        __syncthreads();
        for (int j = t; j < 2048; j += 256) {    // 16 rows x 128 float4
            int row = j >> 7, c4 = j & 127;
            int p = p_base + rf * 16 + row;
            if (p < hi) {
                float4 v = *reinterpret_cast<const float4*>(&rows[row * 516 + c4 * 4]);
                *reinterpret_cast<float4*>(tp + (size_t)(p - lo) * 512 + c4 * 4) = v;
            }
        }
        __syncthreads();
    }
}

// ---------------------------------------------------------------------------
// Gather segment-sum: one block per receiver node, thread t owns channel u=t.
// Reads contiguous tp_w rows + sender s_up/v_up; accumulates in registers;
// writes ms/mv exclusively (+= across chunk launches). ZERO atomics.
// ---------------------------------------------------------------------------
__global__ __launch_bounds__(128) void k_gather(
    const float* __restrict__ tp, const int* __restrict__ perm,
    const int* __restrict__ row_ptr, const int* __restrict__ edge_index,
    const float* __restrict__ edge_attrs,
    const float* __restrict__ s_up, const float* __restrict__ v_up,
    float* __restrict__ ms, float* __restrict__ mv, int lo, int hi)
{
    int n = blockIdx.x;
    int p0 = row_ptr[n], p1 = row_ptr[n + 1];
    if (p0 < lo) p0 = lo;
    if (p1 > hi) p1 = hi;
    if (p0 >= p1) return;
    const int u = threadIdx.x;   // 0..127
    float ms0 = 0.f, ms1 = 0.f, a0 = 0.f, a1 = 0.f, a2 = 0.f;
    float b0 = 0.f, b1 = 0.f, b2 = 0.f;
    for (int p = p0; p < p1; ++p) {
        int e = perm[p];
        int sn = edge_index[e];
        float y0  = edge_attrs[e * 4 + 0];
        float y1a = edge_attrs[e * 4 + 1];
        float y1b = edge_attrs[e * 4 + 2];
        float y1c = edge_attrs[e * 4 + 3];
        const float* tr = tp + (size_t)(p - lo) * 512;
        float wA = tr[u], wB = tr[128 + u], wC = tr[256 + u], wD = tr[384 + u];
        float xs = s_up[sn * 128 + u];
        const float* xvp = v_up + sn * 384 + u * 3;
        float xv0 = xvp[0], xv1 = xvp[1], xv2 = xvp[2];
        ms0 += wA * xs * y0;
        float dot = xv0 * y1a + xv1 * y1b + xv2 * y1c;
        ms1 += wD * dot * INV_SQRT3;
        float q = wB * xs * INV_SQRT3;
        a0 += q * y1a; a1 += q * y1b; a2 += q * y1c;
        float r = wC * y0 * INV_SQRT3;
        b0 += r * xv0; b1 += r * xv1; b2 += r * xv2;
    }
    float* msp = ms + (size_t)n * 256;
    msp[u] += ms0; msp[128 + u] += ms1;
    float* mvp = mv + (size_t)n * 768 + u * 3;
    mvp[0] += a0; mvp[1] += a1; mvp[2] += a2;
    mvp[384] += b0; mvp[385] += b1; mvp[386] += b2;
}

// ---------------------------------------------------------------------------
// Kernel 3: node-level post-GEMMs (unchanged).
// ---------------------------------------------------------------------------
__global__ __launch_bounds__(256) void k_node_post(
    const float* __restrict__ ms, const float* __restrict__ mv,
    const float* __restrict__ W_lin0, const float* __restrict__ W_lin1,
    float* __restrict__ msg)
{
    __shared__ float ms_lds[8][256];
    __shared__ float mv_lds[8][768];
    const int n0 = blockIdx.x * 8;
    const int t = threadIdx.x;

    for (int idx = t; idx < 8 * 256; idx += 256) {
        int nn = idx >> 8, c4 = idx & 255;
        if (c4 < 64) {
            float4 v = ((const float4*)ms)[(size_t)(n0 + nn) * 64 + c4];
            int c = c4 * 4;
            ms_lds[nn][c] = v.x; ms_lds[nn][c + 1] = v.y;
            ms_lds[nn][c + 2] = v.z; ms_lds[nn][c + 3] = v.w;
        } else {
            int q = c4 - 64;
            float4 v = ((const float4*)mv)[(size_t)(n0 + nn) * 192 + q];
            int c = q * 4;
            mv_lds[nn][c] = v.x; mv_lds[nn][c + 1] = v.y;
            mv_lds[nn][c + 2] = v.z; mv_lds[nn][c + 3] = v.w;
        }
    }
    __syncthreads();

    for (int o = t; o < 512; o += 256) {
        float acc[8] = {0,0,0,0,0,0,0,0};
        if (o < 128) {
            int m = o;
            for (int c = 0; c < 256; ++c) {
                float w = W_lin0[c * 128 + m];
                #pragma unroll
                for (int nn = 0; nn < 8; ++nn) acc[nn] += ms_lds[nn][c] * w;
            }
            #pragma unroll
            for (int nn = 0; nn < 8; ++nn)
                msg[(size_t)(n0 + nn) * 512 + m * 4] = acc[nn] * INV_M;
        } else {
            int ov = o - 128;
            int i = ov >> 7, m = ov & 127;
            for (int c = 0; c < 256; ++c) {
                float w = W_lin1[c * 128 + m];
                #pragma unroll
                for (int nn = 0; nn < 8; ++nn) acc[nn] += mv_lds[nn][c * 3 + i] * w;
            }
            #pragma unroll
            for (int nn = 0; nn < 8; ++nn)
                msg[(size_t)(n0 + nn) * 512 + m * 4 + 1 + i] = acc[nn] * INV_M;
        }
    }
}

// ---------------------------------------------------------------------------
extern "C" void kernel_launch(void* const* d_in, const int* in_sizes, int n_in,
                              void* d_out, int out_size, void* d_ws, size_t ws_size,
                              hipStream_t stream) {
    (void)in_sizes; (void)n_in; (void)out_size;

    const float* node_feats = (const float*)d_in[1];
    const float* edge_attrs = (const float*)d_in[2];
    const float* edge_feats = (const float*)d_in[3];
    const int*   edge_index = (const int*)d_in[4];
    const float* W_up0   = (const float*)d_in[5];
    const float* W_up1   = (const float*)d_in[6];
    const float* W_down  = (const float*)d_in[7];
    const float* mlp_w0  = (const float*)d_in[8];
    const float* mlp_w1  = (const float*)d_in[9];
    const float* mlp_w2  = (const float*)d_in[10];
    const float* mlp_w3  = (const float*)d_in[11];
    const float* W_lin0  = (const float*)d_in[12];
    const float* W_lin1  = (const float*)d_in[13];
    const float* W_skip0 = (const float*)d_in[14];
    const float* W_skip1 = (const float*)d_in[15];

    float* out = (float*)d_out;
    float* msg = out;                        // 10.24 MB, written LAST
    float* sc  = out + N_NODES * 512;

    // msg region hosts (all dead before k_node_post): wt, CSR, fallback tp_w
    char* outb = (char*)d_out;
    __bf16* wt   = (__bf16*)outb;
    int* cursor  = (int*)(outb + CUR_OFF);
    int* row_ptr = (int*)(outb + RP_OFF);
    int* perm    = (int*)(outb + PERM_OFF);

    // ws: fixed 30.72 MB + optional tp_w chunk
    float* s_up = (float*)d_ws;              // 640,000 f
    float* v_up = s_up + N_NODES * 128;      // 1,920,000 f
    float* down = v_up + N_NODES * 384;      // 320,000 f
    float* ms   = down + N_NODES * 64;       // 1,280,000 f
    float* mv   = ms + N_NODES * 256;        // 3,840,000 f -> end 8,000,000 f
    const size_t fixed_f = 8000000;

    // choose tp_w chunk placement/size from ws_size (runtime, same every call)
    long long spare = (long long)ws_size - (long long)(fixed_f * 4);
    long long ecws = (spare > 0) ? ((spare / 2048) & ~31LL) : 0;
    float* tp; int Ec;
    if (ecws >= 4608) {
        Ec = (int)(ecws > N_EDGES ? N_EDGES : ecws);
        tp = (float*)d_ws + fixed_f;
    } else {
        Ec = TPM_EC;
        tp = (float*)(outb + TPM_OFF);
    }

    hipMemsetAsync(ms, 0, (size_t)(N_NODES * 256 + N_NODES * 768) * sizeof(float), stream);
    hipMemsetAsync(cursor, 0, N_NODES * sizeof(int), stream);

    k_prep_w<<<1184, 256, 0, stream>>>(mlp_w0, mlp_w1, mlp_w2, mlp_w3, wt);
    k_hist<<<(N_EDGES + 255) / 256, 256, 0, stream>>>(edge_index, cursor, perm);
    k_node_pre<<<N_NODES / 8, 256, 0, stream>>>(
        node_feats, W_up0, W_up1, W_down, W_skip0, W_skip1,
        s_up, v_up, down, sc);
    k_scan<<<1, 1024, 0, stream>>>(cursor, row_ptr);
    k_scatter<<<(N_EDGES + 255) / 256, 256, 0, stream>>>(edge_index, cursor, perm);

    for (int lo = 0; lo < N_EDGES; lo += Ec) {
        int hi = lo + Ec; if (hi > N_EDGES) hi = N_EDGES;
        int nb = (hi - lo + 31) / 32;
        k_mlp<<<nb, 256, 0, stream>>>(edge_feats, edge_index, wt, down, perm, tp, lo, hi);
        k_gather<<<N_NODES, 128, 0, stream>>>(tp, perm, row_ptr, edge_index,
                                              edge_attrs, s_up, v_up, ms, mv, lo, hi);
    }

    k_node_post<<<N_NODES / 8, 256, 0, stream>>>(ms, mv, W_lin0, W_lin1, msg);
}